// Round 2
// baseline (463.418 us; speedup 1.0000x reference)
//
#include <hip/hip_runtime.h>

// Problem constants
#define Bn   4
#define Cc   256
#define Hh   128
#define Ww   256
#define HWp  32768          // H*W
#define CQK  64
#define COUT 256

typedef _Float16 half8 __attribute__((ext_vector_type(8)));
typedef _Float16 half4 __attribute__((ext_vector_type(4)));
typedef float   floatx4 __attribute__((ext_vector_type(4)));

#define MFMA16(a, b, c) __builtin_amdgcn_mfma_f32_16x16x32_f16((a), (b), (c), 0, 0, 0)

// ---------------------------------------------------------------------------
// Kernel 0: convert W (fp32) -> f16 in MFMA *fragment order*:
//   W16f[mt16][ks][lane] . 8 halves,  mt16 = 16-row tile over [Wq|Wk|Wv] (24),
//   lane = quad*16+l16 encodes (row l16, 16B col-chunk quad), ks = 64B col step.
// A wave's a[ks] fragment load is then one contiguous 1KB transaction.
// Stored in the tail of d_out (k_attn rewrites all of out afterwards).
// ---------------------------------------------------------------------------
__global__ __launch_bounds__(256) void k_wcvt(
    const float* __restrict__ Wq, const float* __restrict__ Wk,
    const float* __restrict__ Wv, _Float16* __restrict__ W16f)
{
    const int g    = blockIdx.x * 256 + threadIdx.x;  // 16B-chunk id, 0..12287
    const int mt16 = g >> 9;
    const int ks   = (g >> 6) & 7;
    const int lane = g & 63;
    const int quad = lane >> 4;
    const int l16  = lane & 15;
    const int R    = mt16 * 16 + l16;                 // row in concat space 0..383
    const int c0   = ks * 32 + quad * 8;
    const float* src;
    if (R < 64)       src = Wq + (size_t)R * 256 + c0;
    else if (R < 128) src = Wk + (size_t)(R - 64) * 256 + c0;
    else              src = Wv + (size_t)(R - 128) * 256 + c0;
    float4 f0 = *(const float4*)src;
    float4 f1 = *(const float4*)(src + 4);
    half8 h = {(_Float16)f0.x, (_Float16)f0.y, (_Float16)f0.z, (_Float16)f0.w,
               (_Float16)f1.x, (_Float16)f1.y, (_Float16)f1.z, (_Float16)f1.w};
    *(half8*)&W16f[(size_t)g * 8] = h;
}

// x_lds column swizzle: conflict-free for both the 4px-transpose writes and the
// b-fragment half8 reads.
__device__ __forceinline__ int xswz(int row) { return ((row ^ (row >> 2)) & 7) << 3; }

// ---------------------------------------------------------------------------
// One 32-row m-tile: A frags from fragment-ordered W16f (coalesced, L2-hot),
// B frags from swizzled x_lds, bias + store epilogue.
// ---------------------------------------------------------------------------
template<int DSTMODE>
__device__ __forceinline__ void do_mtile(
    const _Float16* __restrict__ W16f, const _Float16* x_lds,
    int mt16, const float* __restrict__ bsel, int mbase,
    _Float16* __restrict__ dst, int b, int pb,
    int wv, int quad, int l16, int lane,
    int rowb0, int rowb1, int sw0, int sw1, int n0)
{
    half8 a[8];
    const _Float16* ap = W16f + ((size_t)mt16 * 512 + lane) * 8;
    #pragma unroll
    for (int ks = 0; ks < 8; ++ks)
        a[ks] = *(const half8*)(ap + ks * 512);

    floatx4 acc0 = {0.f, 0.f, 0.f, 0.f};
    floatx4 acc1 = {0.f, 0.f, 0.f, 0.f};
    #pragma unroll
    for (int ks = 0; ks < 8; ++ks) {
        half8 b0 = *(const half8*)&x_lds[rowb0 * 256 + ((ks * 32 + quad * 8) ^ sw0)];
        half8 b1 = *(const half8*)&x_lds[rowb1 * 256 + ((ks * 32 + quad * 8) ^ sw1)];
        acc0 = MFMA16(a[ks], b0, acc0);
        acc1 = MFMA16(a[ks], b1, acc1);
    }

    const int mloc = 16 * (wv & 1) + quad * 4;
    float4 bi = *(const float4*)&bsel[mbase + mloc];
    const float bia[4] = {bi.x, bi.y, bi.z, bi.w};
    if (DSTMODE == 0) {
        #pragma unroll
        for (int nt = 0; nt < 2; ++nt) {
            floatx4 acc = nt ? acc1 : acc0;
            const int pix = pb + n0 + nt * 16 + l16;
            half4 h = (half4){(_Float16)(acc[0] + bia[0]), (_Float16)(acc[1] + bia[1]),
                              (_Float16)(acc[2] + bia[2]), (_Float16)(acc[3] + bia[3])};
            *(half4*)&dst[((size_t)b * HWp + pix) * 64 + mbase + mloc] = h;
        }
    } else {
        #pragma unroll
        for (int nt = 0; nt < 2; ++nt) {
            floatx4 acc = nt ? acc1 : acc0;
            const int pix = pb + n0 + nt * 16 + l16;
            #pragma unroll
            for (int r = 0; r < 4; ++r) {
                const int o = mbase + mloc + r;
                dst[((size_t)b * 256 + o) * HWp + pix] = (_Float16)(acc[r] + bia[r]);
            }
        }
    }
}

// ---------------------------------------------------------------------------
// Kernel 1: Q/K/V 1x1-conv projections.
//   Qws, Kws: pixel-major [b][pix][64];  Vws: channel-major [b][o][pix]
// grid: (512 pixel-tiles of 64, B, 2 jobs: 0=Q from de_out, 1=K+V from flow)
// A frags from fragment-ordered W16f (1KB coalesced per wave-load), no w_lds,
// one barrier total.  Compile-time loop trip counts (Qx2 / Kx2 / Vx8).
// ---------------------------------------------------------------------------
__global__ __launch_bounds__(256, 4) void k_qkv(
    const float* __restrict__ flow, const float* __restrict__ de_out,
    const _Float16* __restrict__ W16f,
    const float* __restrict__ bq, const float* __restrict__ bk,
    const float* __restrict__ bv,
    _Float16* __restrict__ Qws, _Float16* __restrict__ Kws,
    _Float16* __restrict__ Vws)
{
    __shared__ __align__(16) _Float16 x_lds[64 * 256];   // [pix][c], swizzled

    const int t   = threadIdx.x;
    const int b   = blockIdx.y;
    const int job = blockIdx.z;
    const int pb  = blockIdx.x * 64;  // pixel base in [0, HW)

    const float* X = (job == 0 ? de_out : flow) + (size_t)b * Cc * HWp;

    // ---- stage X tile: [256 c][64 px] fp32 -> transposed f16 x_lds[px][c]
    {
        const int px4 = t & 15;   // pixel quad index
        const int cg  = t >> 4;   // 0..15
        #pragma unroll
        for (int rep = 0; rep < 4; ++rep) {
            const int c0 = 4 * cg + 64 * rep;
            float4 r0 = *(const float4*)&X[(size_t)(c0 + 0) * HWp + pb + 4 * px4];
            float4 r1 = *(const float4*)&X[(size_t)(c0 + 1) * HWp + pb + 4 * px4];
            float4 r2 = *(const float4*)&X[(size_t)(c0 + 2) * HWp + pb + 4 * px4];
            float4 r3 = *(const float4*)&X[(size_t)(c0 + 3) * HWp + pb + 4 * px4];
            const int r = 4 * px4;
            half4 h;
            h = (half4){(_Float16)r0.x, (_Float16)r1.x, (_Float16)r2.x, (_Float16)r3.x};
            *(half4*)&x_lds[(r + 0) * 256 + (c0 ^ xswz(r + 0))] = h;
            h = (half4){(_Float16)r0.y, (_Float16)r1.y, (_Float16)r2.y, (_Float16)r3.y};
            *(half4*)&x_lds[(r + 1) * 256 + (c0 ^ xswz(r + 1))] = h;
            h = (half4){(_Float16)r0.z, (_Float16)r1.z, (_Float16)r2.z, (_Float16)r3.z};
            *(half4*)&x_lds[(r + 2) * 256 + (c0 ^ xswz(r + 2))] = h;
            h = (half4){(_Float16)r0.w, (_Float16)r1.w, (_Float16)r2.w, (_Float16)r3.w};
            *(half4*)&x_lds[(r + 3) * 256 + (c0 ^ xswz(r + 3))] = h;
        }
    }
    __syncthreads();   // the only barrier in this kernel

    const int wv   = t >> 6;
    const int lane = t & 63;
    const int quad = lane >> 4;
    const int l16  = lane & 15;
    const int n0   = (wv >> 1) * 32;
    const int wlo  = wv & 1;

    const int rowb0 = n0 + l16;
    const int rowb1 = n0 + 16 + l16;
    const int sw0 = xswz(rowb0);
    const int sw1 = xswz(rowb1);

    if (job == 0) {
        #pragma unroll
        for (int mt = 0; mt < 2; ++mt)
            do_mtile<0>(W16f, x_lds, mt * 2 + wlo, bq, mt * 32, Qws, b, pb,
                        wv, quad, l16, lane, rowb0, rowb1, sw0, sw1, n0);
    } else {
        #pragma unroll
        for (int mt = 0; mt < 2; ++mt)
            do_mtile<0>(W16f, x_lds, 4 + mt * 2 + wlo, bk, mt * 32, Kws, b, pb,
                        wv, quad, l16, lane, rowb0, rowb1, sw0, sw1, n0);
        #pragma unroll
        for (int mt = 0; mt < 8; ++mt)
            do_mtile<1>(W16f, x_lds, 8 + mt * 2 + wlo, bv, mt * 32, Vws, b, pb,
                        wv, quad, l16, lane, rowb0, rowb1, sw0, sw1, n0);
    }
}

// ---------------------------------------------------------------------------
// Kernel 2: width-axial attention per (b,h) row.  (unchanged this round)
// ---------------------------------------------------------------------------
__global__ __launch_bounds__(256, 2) void k_attn(
    const _Float16* __restrict__ Qws, const _Float16* __restrict__ Kws,
    const _Float16* __restrict__ Vws, float* __restrict__ out)
{
    __shared__ __align__(16) _Float16 k_lds[256 * 64];    // [w'][d] swizzled, 32 KB
    __shared__ __align__(16) _Float16 att_lds[32 * 256];  // [w][w'] swizzled, 16 KB
    __shared__ float inv_l[32];

    const int t    = threadIdx.x;
    const int h    = blockIdx.x;
    const int b    = blockIdx.y;
    const int wv   = t >> 6;
    const int lane = t & 63;
    const int quad = lane >> 4;
    const int l16  = lane & 15;
    const size_t pixbase = (size_t)b * HWp + h * 256;

    // ---- V fragments into registers: o = os*64 + 16*wv + l16, w' chunk ks*32+quad*8
    half8 vf[4][8];
    #pragma unroll
    for (int os = 0; os < 4; ++os)
        #pragma unroll
        for (int ks = 0; ks < 8; ++ks)
            vf[os][ks] = *(const half8*)&Vws[((size_t)b * 256 + os * 64 + 16 * wv + l16) * HWp
                                             + h * 256 + ks * 32 + quad * 8];

    // ---- stage K once: 256 rows x 64 d, swizzled
    #pragma unroll
    for (int i = 0; i < 8; ++i) {
        const int g = t + 256 * i;
        const int row = g >> 3, off = (g & 7) * 8;
        *(half8*)&k_lds[row * 64 + (off ^ ((row & 7) << 3))] =
            *(const half8*)&Kws[(pixbase + row) * 64 + off];
    }
    __syncthreads();

    const int wt  = wv & 1;              // w-tile of this wave
    const int swq = (l16 & 7) << 3;      // row-parity swizzle (rows l16, 16+l16 share it)

    for (int chunk = 0; chunk < 8; ++chunk) {
        if (chunk) __syncthreads();      // protect att_lds/inv_l reuse

        // ---- energy, transposed: D[w'][w] = mfma(K-rows, Q-rows) -> att_lds[w][w']
        {
            const size_t qrow = pixbase + chunk * 32 + wt * 16 + l16;
            half8 bq0 = *(const half8*)&Qws[qrow * 64 + quad * 8];
            half8 bq1 = *(const half8*)&Qws[qrow * 64 + 32 + quad * 8];
            #pragma unroll
            for (int j = 0; j < 8; ++j) {
                const int nt = (wv >> 1) * 8 + j;      // w'-tile
                const int krow = nt * 16 + l16;
                half8 a0 = *(const half8*)&k_lds[krow * 64 + ((quad * 8) ^ swq)];
                half8 a1 = *(const half8*)&k_lds[krow * 64 + ((32 + quad * 8) ^ swq)];
                floatx4 acc = {0.f, 0.f, 0.f, 0.f};
                acc = MFMA16(a0, bq0, acc);
                acc = MFMA16(a1, bq1, acc);
                half4 hv = (half4){(_Float16)acc[0], (_Float16)acc[1],
                                   (_Float16)acc[2], (_Float16)acc[3]};
                *(half4*)&att_lds[(wt * 16 + l16) * 256 + ((nt * 16 + quad * 4) ^ swq)] = hv;
            }
        }
        __syncthreads();

        // ---- softmax over w' (256), 8 threads per row, fp32 math
        {
            const int r = t >> 3, seg = t & 7;
            const int sw = (r & 7) << 3;
            _Float16* base = &att_lds[r * 256];
            half8 v[4];
            float mx = -1e30f;
            #pragma unroll
            for (int u = 0; u < 4; ++u) {
                v[u] = *(const half8*)&base[(seg * 32 + u * 8) ^ sw];
                #pragma unroll
                for (int e = 0; e < 8; ++e) mx = fmaxf(mx, (float)v[u][e]);
            }
            mx = fmaxf(mx, __shfl_xor(mx, 1));
            mx = fmaxf(mx, __shfl_xor(mx, 2));
            mx = fmaxf(mx, __shfl_xor(mx, 4));
            float s = 0.f;
            #pragma unroll
            for (int u = 0; u < 4; ++u) {
                half8 ex;
                #pragma unroll
                for (int e = 0; e < 8; ++e) {
                    const float p = __expf((float)v[u][e] - mx);
                    s += p;
                    ex[e] = (_Float16)p;
                }
                *(half8*)&base[(seg * 32 + u * 8) ^ sw] = ex;
            }
            s += __shfl_xor(s, 1);
            s += __shfl_xor(s, 2);
            s += __shfl_xor(s, 4);
            if (seg == 0) inv_l[r] = 1.f / s;
        }
        __syncthreads();

        // ---- PV: O[o][w] = sum_w' V[o][w'] * att[w][w'], V from registers
        {
            floatx4 acc[4][2];
            #pragma unroll
            for (int os = 0; os < 4; ++os) {
                acc[os][0] = (floatx4){0.f, 0.f, 0.f, 0.f};
                acc[os][1] = (floatx4){0.f, 0.f, 0.f, 0.f};
            }
            #pragma unroll
            for (int ks = 0; ks < 8; ++ks) {
                half8 p0 = *(const half8*)&att_lds[l16 * 256 + ((ks * 32 + quad * 8) ^ swq)];
                half8 p1 = *(const half8*)&att_lds[(16 + l16) * 256 + ((ks * 32 + quad * 8) ^ swq)];
                #pragma unroll
                for (int os = 0; os < 4; ++os) {
                    acc[os][0] = MFMA16(vf[os][ks], p0, acc[os][0]);
                    acc[os][1] = MFMA16(vf[os][ks], p1, acc[os][1]);
                }
            }
            const float il0 = inv_l[l16];
            const float il1 = inv_l[16 + l16];
            const int wg = chunk * 32 + l16;
            #pragma unroll
            for (int os = 0; os < 4; ++os) {
                const int og = os * 64 + 16 * wv + quad * 4;
                #pragma unroll
                for (int r = 0; r < 4; ++r) {
                    out[(((size_t)b * 256 + og + r) * Hh + h) * Ww + wg]      = acc[os][0][r] * il0;
                    out[(((size_t)b * 256 + og + r) * Hh + h) * Ww + 16 + wg] = acc[os][1][r] * il1;
                }
            }
        }
    }
}

// ---------------------------------------------------------------------------
extern "C" void kernel_launch(void* const* d_in, const int* in_sizes, int n_in,
                              void* d_out, int out_size, void* d_ws, size_t ws_size,
                              hipStream_t stream)
{
    const float* flow   = (const float*)d_in[0];
    const float* de_out = (const float*)d_in[1];
    const float* Wq = (const float*)d_in[2];
    const float* bq = (const float*)d_in[3];
    const float* Wk = (const float*)d_in[4];
    const float* bk = (const float*)d_in[5];
    const float* Wv = (const float*)d_in[6];
    const float* bv = (const float*)d_in[7];

    _Float16* Qws = (_Float16*)d_ws;
    _Float16* Kws = Qws + (size_t)Bn * HWp * 64;
    _Float16* Vws = Kws + (size_t)Bn * HWp * 64;
    float* out = (float*)d_out;

    // fragment-ordered f16 weights live in the tail of d_out (192 KB);
    // k_attn overwrites every element of out afterwards, so this is scratch.
    _Float16* W16f = (_Float16*)((char*)d_out + (size_t)out_size - 98304 * sizeof(_Float16));

    k_wcvt<<<dim3(48), 256, 0, stream>>>(Wq, Wk, Wv, W16f);

    dim3 g1(HWp / 64, Bn, 2);
    k_qkv<<<g1, 256, 0, stream>>>(flow, de_out, W16f, bq, bk, bv, Qws, Kws, Vws);

    dim3 g2(Hh, Bn);
    k_attn<<<g2, 256, 0, stream>>>(Qws, Kws, Vws, out);
}

// Round 3
// 400.138 us; speedup vs baseline: 1.1581x; 1.1581x over previous
//
#include <hip/hip_runtime.h>

// Problem constants
#define Bn   4
#define Cc   256
#define Hh   128
#define Ww   256
#define HWp  32768          // H*W
#define CQK  64
#define COUT 256

typedef _Float16 half8 __attribute__((ext_vector_type(8)));
typedef _Float16 half4 __attribute__((ext_vector_type(4)));
typedef float   floatx4 __attribute__((ext_vector_type(4)));

#define MFMA16(a, b, c) __builtin_amdgcn_mfma_f32_16x16x32_f16((a), (b), (c), 0, 0, 0)

// ---------------------------------------------------------------------------
// Kernel 0: convert W (fp32) -> f16 in MFMA *fragment order*:
//   W16f[mt16][ks][lane] . 8 halves,  mt16 = 16-row tile over [Wq|Wk|Wv] (24),
//   lane = quad*16+l16 encodes (row l16, 16B col-chunk quad), ks = 64B col step.
// A wave's a[ks] fragment load is then one contiguous 1KB transaction.
// Stored in the tail of d_out (k_attn rewrites all of out afterwards).
// ---------------------------------------------------------------------------
__global__ __launch_bounds__(256) void k_wcvt(
    const float* __restrict__ Wq, const float* __restrict__ Wk,
    const float* __restrict__ Wv, _Float16* __restrict__ W16f)
{
    const int g    = blockIdx.x * 256 + threadIdx.x;  // 16B-chunk id, 0..12287
    const int mt16 = g >> 9;
    const int ks   = (g >> 6) & 7;
    const int lane = g & 63;
    const int quad = lane >> 4;
    const int l16  = lane & 15;
    const int R    = mt16 * 16 + l16;                 // row in concat space 0..383
    const int c0   = ks * 32 + quad * 8;
    const float* src;
    if (R < 64)       src = Wq + (size_t)R * 256 + c0;
    else if (R < 128) src = Wk + (size_t)(R - 64) * 256 + c0;
    else              src = Wv + (size_t)(R - 128) * 256 + c0;
    float4 f0 = *(const float4*)src;
    float4 f1 = *(const float4*)(src + 4);
    half8 h = {(_Float16)f0.x, (_Float16)f0.y, (_Float16)f0.z, (_Float16)f0.w,
               (_Float16)f1.x, (_Float16)f1.y, (_Float16)f1.z, (_Float16)f1.w};
    *(half8*)&W16f[(size_t)g * 8] = h;
}

// x_lds column swizzle: conflict-free for both the 4px-transpose writes and the
// b-fragment half8 reads.
__device__ __forceinline__ int xswz(int row) { return ((row ^ (row >> 2)) & 7) << 3; }

// ---------------------------------------------------------------------------
// Kernel 1: Q/K/V 1x1-conv projections.
//   Qws, Kws: pixel-major [b][pix][64];  Vws: channel-major [b][o][pix]
// grid: (512 pixel-tiles of 64, B, 2 jobs: 0=Q from de_out, 1=K+V from flow)
// Runtime mt loop (unroll 1) keeps per-tile stores in lockstep so 128-B output
// lines coalesce in L2 (round-2 full unroll tripled WRITE_SIZE).  A-fragments
// from fragment-ordered W16f: one 1KB coalesced wave-load per ks, prefetched
// one tile ahead to hide L2 latency under the MFMA chain.  One barrier total.
// ---------------------------------------------------------------------------
__global__ __launch_bounds__(256, 4) void k_qkv(
    const float* __restrict__ flow, const float* __restrict__ de_out,
    const _Float16* __restrict__ W16f,
    const float* __restrict__ bq, const float* __restrict__ bk,
    const float* __restrict__ bv,
    _Float16* __restrict__ Qws, _Float16* __restrict__ Kws,
    _Float16* __restrict__ Vws)
{
    __shared__ __align__(16) _Float16 x_lds[64 * 256];   // [pix][c], swizzled

    const int t   = threadIdx.x;
    const int b   = blockIdx.y;
    const int job = blockIdx.z;
    const int pb  = blockIdx.x * 64;  // pixel base in [0, HW)

    const float* X = (job == 0 ? de_out : flow) + (size_t)b * Cc * HWp;

    // ---- stage X tile: [256 c][64 px] fp32 -> transposed f16 x_lds[px][c]
    {
        const int px4 = t & 15;   // pixel quad index
        const int cg  = t >> 4;   // 0..15
        #pragma unroll
        for (int rep = 0; rep < 4; ++rep) {
            const int c0 = 4 * cg + 64 * rep;
            float4 r0 = *(const float4*)&X[(size_t)(c0 + 0) * HWp + pb + 4 * px4];
            float4 r1 = *(const float4*)&X[(size_t)(c0 + 1) * HWp + pb + 4 * px4];
            float4 r2 = *(const float4*)&X[(size_t)(c0 + 2) * HWp + pb + 4 * px4];
            float4 r3 = *(const float4*)&X[(size_t)(c0 + 3) * HWp + pb + 4 * px4];
            const int r = 4 * px4;
            half4 h;
            h = (half4){(_Float16)r0.x, (_Float16)r1.x, (_Float16)r2.x, (_Float16)r3.x};
            *(half4*)&x_lds[(r + 0) * 256 + (c0 ^ xswz(r + 0))] = h;
            h = (half4){(_Float16)r0.y, (_Float16)r1.y, (_Float16)r2.y, (_Float16)r3.y};
            *(half4*)&x_lds[(r + 1) * 256 + (c0 ^ xswz(r + 1))] = h;
            h = (half4){(_Float16)r0.z, (_Float16)r1.z, (_Float16)r2.z, (_Float16)r3.z};
            *(half4*)&x_lds[(r + 2) * 256 + (c0 ^ xswz(r + 2))] = h;
            h = (half4){(_Float16)r0.w, (_Float16)r1.w, (_Float16)r2.w, (_Float16)r3.w};
            *(half4*)&x_lds[(r + 3) * 256 + (c0 ^ xswz(r + 3))] = h;
        }
    }
    __syncthreads();   // the only barrier in this kernel

    const int wv   = t >> 6;
    const int lane = t & 63;
    const int quad = lane >> 4;
    const int l16  = lane & 15;
    const int n0   = (wv >> 1) * 32;
    const int wlo  = wv & 1;
    const int nmt  = (job == 0) ? 2 : 10;

    const int rowb0 = n0 + l16;
    const int rowb1 = n0 + 16 + l16;
    const int sw0 = xswz(rowb0);
    const int sw1 = xswz(rowb1);

    // mt -> 16-row fragment tile in W16f concat space
    auto tile16 = [&](int mt) -> int {
        if (job == 0)  return mt * 2 + wlo;            // Wq rows
        if (mt < 2)    return 4 + mt * 2 + wlo;        // Wk rows
        return 8 + (mt - 2) * 2 + wlo;                 // Wv rows
    };

    const _Float16* apbase = W16f + (size_t)lane * 8;

    // preload tile 0 A-fragments (one coalesced 1KB wave-load per ks)
    half8 a[8];
    {
        const size_t o0 = (size_t)tile16(0) * 4096;
        #pragma unroll
        for (int ks = 0; ks < 8; ++ks)
            a[ks] = *(const half8*)(apbase + o0 + ks * 512);
    }

    #pragma unroll 1
    for (int mt = 0; mt < nmt; ++mt) {
        // prefetch next tile's A-fragments (last iter: re-load current, L2-hot)
        half8 an[8];
        {
            const int mtn = (mt + 1 < nmt) ? mt + 1 : mt;
            const size_t on = (size_t)tile16(mtn) * 4096;
            #pragma unroll
            for (int ks = 0; ks < 8; ++ks)
                an[ks] = *(const half8*)(apbase + on + ks * 512);
        }

        floatx4 acc0 = {0.f, 0.f, 0.f, 0.f};
        floatx4 acc1 = {0.f, 0.f, 0.f, 0.f};
        #pragma unroll
        for (int ks = 0; ks < 8; ++ks) {
            half8 b0 = *(const half8*)&x_lds[rowb0 * 256 + ((ks * 32 + quad * 8) ^ sw0)];
            half8 b1 = *(const half8*)&x_lds[rowb1 * 256 + ((ks * 32 + quad * 8) ^ sw1)];
            acc0 = MFMA16(a[ks], b0, acc0);
            acc1 = MFMA16(a[ks], b1, acc1);
        }

        // epilogue: runtime dst select (keeps loop un-unrolled, stores lockstep)
        int mbase, dstmode;
        const float* bsel;
        _Float16* dst;
        if (job == 0)     { mbase = mt * 32;       bsel = bq; dst = Qws; dstmode = 0; }
        else if (mt < 2)  { mbase = mt * 32;       bsel = bk; dst = Kws; dstmode = 0; }
        else              { mbase = (mt - 2) * 32; bsel = bv; dst = Vws; dstmode = 1; }

        const int mloc = 16 * wlo + quad * 4;
        float4 bi = *(const float4*)&bsel[mbase + mloc];
        const float bia[4] = {bi.x, bi.y, bi.z, bi.w};
        if (dstmode == 0) {
            #pragma unroll
            for (int nt = 0; nt < 2; ++nt) {
                floatx4 acc = nt ? acc1 : acc0;
                const int pix = pb + n0 + nt * 16 + l16;
                half4 h = (half4){(_Float16)(acc[0] + bia[0]), (_Float16)(acc[1] + bia[1]),
                                  (_Float16)(acc[2] + bia[2]), (_Float16)(acc[3] + bia[3])};
                *(half4*)&dst[((size_t)b * HWp + pix) * 64 + mbase + mloc] = h;
            }
        } else {
            #pragma unroll
            for (int nt = 0; nt < 2; ++nt) {
                floatx4 acc = nt ? acc1 : acc0;
                const int pix = pb + n0 + nt * 16 + l16;
                #pragma unroll
                for (int r = 0; r < 4; ++r) {
                    const int o = mbase + mloc + r;
                    dst[((size_t)b * 256 + o) * HWp + pix] = (_Float16)(acc[r] + bia[r]);
                }
            }
        }

        #pragma unroll
        for (int ks = 0; ks < 8; ++ks) a[ks] = an[ks];
    }
}

// ---------------------------------------------------------------------------
// Kernel 2: width-axial attention per (b,h) row.  (unchanged this round)
// ---------------------------------------------------------------------------
__global__ __launch_bounds__(256, 2) void k_attn(
    const _Float16* __restrict__ Qws, const _Float16* __restrict__ Kws,
    const _Float16* __restrict__ Vws, float* __restrict__ out)
{
    __shared__ __align__(16) _Float16 k_lds[256 * 64];    // [w'][d] swizzled, 32 KB
    __shared__ __align__(16) _Float16 att_lds[32 * 256];  // [w][w'] swizzled, 16 KB
    __shared__ float inv_l[32];

    const int t    = threadIdx.x;
    const int h    = blockIdx.x;
    const int b    = blockIdx.y;
    const int wv   = t >> 6;
    const int lane = t & 63;
    const int quad = lane >> 4;
    const int l16  = lane & 15;
    const size_t pixbase = (size_t)b * HWp + h * 256;

    // ---- V fragments into registers: o = os*64 + 16*wv + l16, w' chunk ks*32+quad*8
    half8 vf[4][8];
    #pragma unroll
    for (int os = 0; os < 4; ++os)
        #pragma unroll
        for (int ks = 0; ks < 8; ++ks)
            vf[os][ks] = *(const half8*)&Vws[((size_t)b * 256 + os * 64 + 16 * wv + l16) * HWp
                                             + h * 256 + ks * 32 + quad * 8];

    // ---- stage K once: 256 rows x 64 d, swizzled
    #pragma unroll
    for (int i = 0; i < 8; ++i) {
        const int g = t + 256 * i;
        const int row = g >> 3, off = (g & 7) * 8;
        *(half8*)&k_lds[row * 64 + (off ^ ((row & 7) << 3))] =
            *(const half8*)&Kws[(pixbase + row) * 64 + off];
    }
    __syncthreads();

    const int wt  = wv & 1;              // w-tile of this wave
    const int swq = (l16 & 7) << 3;      // row-parity swizzle (rows l16, 16+l16 share it)

    for (int chunk = 0; chunk < 8; ++chunk) {
        if (chunk) __syncthreads();      // protect att_lds/inv_l reuse

        // ---- energy, transposed: D[w'][w] = mfma(K-rows, Q-rows) -> att_lds[w][w']
        {
            const size_t qrow = pixbase + chunk * 32 + wt * 16 + l16;
            half8 bq0 = *(const half8*)&Qws[qrow * 64 + quad * 8];
            half8 bq1 = *(const half8*)&Qws[qrow * 64 + 32 + quad * 8];
            #pragma unroll
            for (int j = 0; j < 8; ++j) {
                const int nt = (wv >> 1) * 8 + j;      // w'-tile
                const int krow = nt * 16 + l16;
                half8 a0 = *(const half8*)&k_lds[krow * 64 + ((quad * 8) ^ swq)];
                half8 a1 = *(const half8*)&k_lds[krow * 64 + ((32 + quad * 8) ^ swq)];
                floatx4 acc = {0.f, 0.f, 0.f, 0.f};
                acc = MFMA16(a0, bq0, acc);
                acc = MFMA16(a1, bq1, acc);
                half4 hv = (half4){(_Float16)acc[0], (_Float16)acc[1],
                                   (_Float16)acc[2], (_Float16)acc[3]};
                *(half4*)&att_lds[(wt * 16 + l16) * 256 + ((nt * 16 + quad * 4) ^ swq)] = hv;
            }
        }
        __syncthreads();

        // ---- softmax over w' (256), 8 threads per row, fp32 math
        {
            const int r = t >> 3, seg = t & 7;
            const int sw = (r & 7) << 3;
            _Float16* base = &att_lds[r * 256];
            half8 v[4];
            float mx = -1e30f;
            #pragma unroll
            for (int u = 0; u < 4; ++u) {
                v[u] = *(const half8*)&base[(seg * 32 + u * 8) ^ sw];
                #pragma unroll
                for (int e = 0; e < 8; ++e) mx = fmaxf(mx, (float)v[u][e]);
            }
            mx = fmaxf(mx, __shfl_xor(mx, 1));
            mx = fmaxf(mx, __shfl_xor(mx, 2));
            mx = fmaxf(mx, __shfl_xor(mx, 4));
            float s = 0.f;
            #pragma unroll
            for (int u = 0; u < 4; ++u) {
                half8 ex;
                #pragma unroll
                for (int e = 0; e < 8; ++e) {
                    const float p = __expf((float)v[u][e] - mx);
                    s += p;
                    ex[e] = (_Float16)p;
                }
                *(half8*)&base[(seg * 32 + u * 8) ^ sw] = ex;
            }
            s += __shfl_xor(s, 1);
            s += __shfl_xor(s, 2);
            s += __shfl_xor(s, 4);
            if (seg == 0) inv_l[r] = 1.f / s;
        }
        __syncthreads();

        // ---- PV: O[o][w] = sum_w' V[o][w'] * att[w][w'], V from registers
        {
            floatx4 acc[4][2];
            #pragma unroll
            for (int os = 0; os < 4; ++os) {
                acc[os][0] = (floatx4){0.f, 0.f, 0.f, 0.f};
                acc[os][1] = (floatx4){0.f, 0.f, 0.f, 0.f};
            }
            #pragma unroll
            for (int ks = 0; ks < 8; ++ks) {
                half8 p0 = *(const half8*)&att_lds[l16 * 256 + ((ks * 32 + quad * 8) ^ swq)];
                half8 p1 = *(const half8*)&att_lds[(16 + l16) * 256 + ((ks * 32 + quad * 8) ^ swq)];
                #pragma unroll
                for (int os = 0; os < 4; ++os) {
                    acc[os][0] = MFMA16(vf[os][ks], p0, acc[os][0]);
                    acc[os][1] = MFMA16(vf[os][ks], p1, acc[os][1]);
                }
            }
            const float il0 = inv_l[l16];
            const float il1 = inv_l[16 + l16];
            const int wg = chunk * 32 + l16;
            #pragma unroll
            for (int os = 0; os < 4; ++os) {
                const int og = os * 64 + 16 * wv + quad * 4;
                #pragma unroll
                for (int r = 0; r < 4; ++r) {
                    out[(((size_t)b * 256 + og + r) * Hh + h) * Ww + wg]      = acc[os][0][r] * il0;
                    out[(((size_t)b * 256 + og + r) * Hh + h) * Ww + 16 + wg] = acc[os][1][r] * il1;
                }
            }
        }
    }
}

// ---------------------------------------------------------------------------
extern "C" void kernel_launch(void* const* d_in, const int* in_sizes, int n_in,
                              void* d_out, int out_size, void* d_ws, size_t ws_size,
                              hipStream_t stream)
{
    const float* flow   = (const float*)d_in[0];
    const float* de_out = (const float*)d_in[1];
    const float* Wq = (const float*)d_in[2];
    const float* bq = (const float*)d_in[3];
    const float* Wk = (const float*)d_in[4];
    const float* bk = (const float*)d_in[5];
    const float* Wv = (const float*)d_in[6];
    const float* bv = (const float*)d_in[7];

    _Float16* Qws = (_Float16*)d_ws;
    _Float16* Kws = Qws + (size_t)Bn * HWp * 64;
    _Float16* Vws = Kws + (size_t)Bn * HWp * 64;
    float* out = (float*)d_out;

    // fragment-ordered f16 weights live in the tail of d_out (192 KB);
    // k_attn overwrites every element of out afterwards, so this is scratch.
    _Float16* W16f = (_Float16*)((char*)d_out + (size_t)out_size - 98304 * sizeof(_Float16));

    k_wcvt<<<dim3(48), 256, 0, stream>>>(Wq, Wk, Wv, W16f);

    dim3 g1(HWp / 64, Bn, 2);
    k_qkv<<<g1, 256, 0, stream>>>(flow, de_out, W16f, bq, bk, bv, Qws, Kws, Vws);

    dim3 g2(Hh, Bn);
    k_attn<<<g2, 256, 0, stream>>>(Qws, Kws, Vws, out);
}